// Round 2
// baseline (577.850 us; speedup 1.0000x reference)
//
#include <hip/hip_runtime.h>

typedef __bf16 bf16;
typedef __bf16 bf16x4 __attribute__((ext_vector_type(4)));
typedef __bf16 bf16x8 __attribute__((ext_vector_type(8)));
typedef float floatx4 __attribute__((ext_vector_type(4)));

#define NN 512
#define CC 128
#define NROW (NN*NN)   // 262144 rows

__device__ __forceinline__ void async16(void* lds, const void* g) {
    __builtin_amdgcn_global_load_lds((const __attribute__((address_space(1))) void*)g,
                                     (__attribute__((address_space(3))) void*)lds, 16, 0, 0);
}
__device__ __forceinline__ void wait_vm0() {
    asm volatile("s_waitcnt vmcnt(0)" ::: "memory");
}
__device__ __forceinline__ float sigmoidf(float x) {
    return 1.f / (1.f + __expf(-x));
}

// ---------------- setup: W' = W*nw (640x128 bf16), t1=sum(nw*W), t2=sum(nb*W); same for p_out ----------------
__global__ void setup_kernel(const float* __restrict__ nin_w, const float* __restrict__ nin_b,
                             const float* __restrict__ g_in_w, const float* __restrict__ p_in_w,
                             const float* __restrict__ g_out_w,
                             const float* __restrict__ nout_w, const float* __restrict__ nout_b,
                             const float* __restrict__ p_out_w,
                             bf16* __restrict__ Wall, float* __restrict__ T1, float* __restrict__ T2,
                             bf16* __restrict__ Pp, float* __restrict__ S1, float* __restrict__ S2) {
    int r = blockIdx.x * 256 + threadIdx.x;
    if (r < 640) {
        const float* src = (r < 256) ? (g_in_w + r*CC)
                         : (r < 512) ? (p_in_w + (r-256)*CC)
                                     : (g_out_w + (r-512)*CC);
        float t1 = 0.f, t2 = 0.f;
        for (int c = 0; c < CC; ++c) {
            float wv = src[c];
            float wn = nin_w[c];
            float bn = nin_b[c];
            Wall[r*CC + c] = (bf16)(wv * wn);
            t1 += wn * wv;
            t2 += bn * wv;
        }
        T1[r] = t1; T2[r] = t2;
    } else if (r < 768) {
        int d = r - 640;
        const float* src = p_out_w + d*CC;
        float t1 = 0.f, t2 = 0.f;
        for (int c = 0; c < CC; ++c) {
            float wv = src[c];
            float wn = nout_w[c];
            float bn = nout_b[c];
            Pp[d*CC + c] = (bf16)(wv * wn);
            t1 += wn * wv;
            t2 += bn * wv;
        }
        S1[d] = t1; S2[d] = t2;
    }
}

// ---------------- k1: fused LN-in + [g_in|p_in|g_out] projections (fp32 x input) ----------------
// block = 256 thr (4 waves), 64 rows/block. LN folded into GEMM epilogue.
// outputs: a_t[c][r], b_t[c][r] (bf16, c-major for tri GEMM), gate[r][d] (bf16).
__global__ __launch_bounds__(256) void k1_ln_proj(
        const float* __restrict__ x, const bf16* __restrict__ Wall,
        const float* __restrict__ T1, const float* __restrict__ T2,
        bf16* __restrict__ a_t, bf16* __restrict__ b_t, bf16* __restrict__ gate) {
    __shared__ char  XS[32768];          // 4 slabs x [64 rows][32 floats], 16B chunks swizzled p = c ^ (row&7)
    __shared__ float MU[64], RS[64];
    __shared__ char  TB[4][640];         // per-wave transpose buffer: [16 c][stride 40B]

    const int t    = threadIdx.x;
    const int w    = t >> 6, lane = t & 63;
    const int col  = lane & 15, quad = lane >> 4;
    const long r0  = (long)blockIdx.x * 64;

    // ---- stage raw fp32 x rows (64 x 128 f32 = 32KB) into 4 k-slabs, source-chunk swizzled
    const char* xg = (const char*)(x + r0 * CC);
    for (int q = 0; q < 8; ++q) {
        int L = q*4096 + t*16;
        int s = L >> 13, row = (L >> 7) & 63, p = (L >> 4) & 7;
        int c = p ^ (row & 7);
        async16(XS + L, xg + row*512 + s*128 + c*16);
    }
    wait_vm0();
    __syncthreads();

    // ---- LN stats (4 threads per row; each sums one slab, phase-offset chunks)
    {
        int row = t >> 2, part = t & 3;
        float sum = 0.f, ss = 0.f;
        for (int ch = 0; ch < 8; ++ch) {
            int p = (ch + row + part*2) & 7;
            floatx4 v = *(const floatx4*)(XS + part*8192 + row*128 + p*16);
            for (int j = 0; j < 4; ++j) { float f = v[j]; sum += f; ss += f*f; }
        }
        sum += __shfl_xor(sum, 1, 64); ss += __shfl_xor(ss, 1, 64);
        sum += __shfl_xor(sum, 2, 64); ss += __shfl_xor(ss, 2, 64);
        float mu  = sum * (1.f/128.f);
        float var = ss  * (1.f/128.f) - mu*mu;
        float rs  = rsqrtf(var + 1e-5f);
        if (part == 0) { MU[row] = mu; RS[row] = rs; }
    }
    __syncthreads();

    // ---- A fragments: fp32 LDS -> bf16 registers
    bf16x8 af[4][4];
    for (int mt = 0; mt < 4; ++mt) {
        int row = mt*16 + col;
        for (int s = 0; s < 4; ++s) {
            floatx4 f0 = *(const floatx4*)(XS + s*8192 + row*128 + (((quad*2+0) ^ (row&7))*16));
            floatx4 f1 = *(const floatx4*)(XS + s*8192 + row*128 + (((quad*2+1) ^ (row&7))*16));
            bf16x8 v;
            v[0]=(bf16)f0[0]; v[1]=(bf16)f0[1]; v[2]=(bf16)f0[2]; v[3]=(bf16)f0[3];
            v[4]=(bf16)f1[0]; v[5]=(bf16)f1[1]; v[6]=(bf16)f1[2]; v[7]=(bf16)f1[3];
            af[mt][s] = v;
        }
    }

    // ---- GEMM: jobs 0..15 = pg (g&p cols job*16..), jobs 16..23 = gate cols
    for (int jj = 0; jj < 6; ++jj) {
        int job = w + jj*4;
        if (job < 16) {
            bf16x8 bg[4], bp[4];
            for (int s = 0; s < 4; ++s) {
                bg[s] = *(const bf16x8*)(Wall + (      job*16 + col)*CC + s*32 + quad*8);
                bp[s] = *(const bf16x8*)(Wall + (256 + job*16 + col)*CC + s*32 + quad*8);
            }
            int dg = job*16 + col, dp = 256 + job*16 + col;
            float t1g = T1[dg], t2g = T2[dg], t1p = T1[dp], t2p = T2[dp];
            bf16* dst = (job < 8) ? a_t : b_t;
            int cbase = (job < 8 ? job : job - 8) * 16;
            for (int mt = 0; mt < 4; ++mt) {
                floatx4 ag = {0.f,0.f,0.f,0.f}, ap = {0.f,0.f,0.f,0.f};
                for (int s = 0; s < 4; ++s) {
                    ag = __builtin_amdgcn_mfma_f32_16x16x32_bf16(af[mt][s], bg[s], ag, 0, 0, 0);
                    ap = __builtin_amdgcn_mfma_f32_16x16x32_bf16(af[mt][s], bp[s], ap, 0, 0, 0);
                }
                bf16x4 pk;
                for (int reg = 0; reg < 4; ++reg) {
                    int m = mt*16 + quad*4 + reg;
                    float rs = RS[m], mu = MU[m];
                    float g = rs*ag[reg] - rs*mu*t1g + t2g;
                    float p = rs*ap[reg] - rs*mu*t1p + t2p;
                    pk[reg] = (bf16)(p * sigmoidf(g));
                }
                // wave-private LDS transpose: [c=col][rows quad*4..+3]
                *(bf16x4*)(TB[w] + col*40 + quad*8) = pk;
                bf16x4 rd = *(const bf16x4*)(TB[w] + (lane >> 2)*40 + (lane & 3)*8);
                int  cg = cbase + (lane >> 2);
                long rg = r0 + mt*16 + (lane & 3)*4;
                *(bf16x4*)(dst + (long)cg * NROW + rg) = rd;
            }
        } else {
            int gc = job - 16;
            bf16x8 bgt[4];
            for (int s = 0; s < 4; ++s)
                bgt[s] = *(const bf16x8*)(Wall + (512 + gc*16 + col)*CC + s*32 + quad*8);
            int dd = 512 + gc*16 + col;
            float t1 = T1[dd], t2 = T2[dd];
            for (int mt = 0; mt < 4; ++mt) {
                floatx4 ac = {0.f,0.f,0.f,0.f};
                for (int s = 0; s < 4; ++s)
                    ac = __builtin_amdgcn_mfma_f32_16x16x32_bf16(af[mt][s], bgt[s], ac, 0, 0, 0);
                for (int reg = 0; reg < 4; ++reg) {
                    int m = mt*16 + quad*4 + reg;
                    float rs = RS[m], mu = MU[m];
                    float g = rs*ac[reg] - rs*mu*t1 + t2;
                    gate[(r0 + m)*CC + gc*16 + col] = (bf16)sigmoidf(g);
                }
            }
        }
    }
}

// ---------------- k2: tri[c] = A_c * B_c^T  (128 independent 512^3 bf16 GEMMs) ----------------
__global__ __launch_bounds__(256) void k2_tri(
        const bf16* __restrict__ a_t, const bf16* __restrict__ b_t, bf16* __restrict__ tri) {
    __shared__ char As[8192], Bs[8192];   // [128 rows][32 bf16], 16B chunks swizzled p = c ^ ((row>>2)&3)
    const int t    = threadIdx.x;
    const int w    = t >> 6, lane = t & 63;
    const int col  = lane & 15, quad = lane >> 4;
    const int c    = blockIdx.y;
    const int i0   = (blockIdx.x >> 2) * 128, j0 = (blockIdx.x & 3) * 128;
    const char* Ac = (const char*)(a_t + (long)c * NROW);
    const char* Bc = (const char*)(b_t + (long)c * NROW);
    const int wm = (w >> 1)*64, wn = (w & 1)*64;

    floatx4 acc[4][4];
    for (int mt = 0; mt < 4; ++mt)
        for (int nt = 0; nt < 4; ++nt) { floatx4 z = {0.f,0.f,0.f,0.f}; acc[mt][nt] = z; }

    for (int k0 = 0; k0 < 512; k0 += 32) {
        __syncthreads();
        for (int q = 0; q < 2; ++q) {
            int L = q*4096 + t*16;
            int row = L >> 6, p = (L >> 4) & 3;
            int cl = p ^ ((row >> 2) & 3);
            async16(As + L, Ac + (i0 + row)*1024 + k0*2 + cl*16);
            async16(Bs + L, Bc + (j0 + row)*1024 + k0*2 + cl*16);
        }
        wait_vm0();
        __syncthreads();
        bf16x8 afr[4], bfr[4];
        for (int mt = 0; mt < 4; ++mt) {
            int row = wm + mt*16 + col;
            afr[mt] = *(const bf16x8*)(As + row*64 + ((quad ^ ((row>>2)&3))*16));
        }
        for (int nt = 0; nt < 4; ++nt) {
            int row = wn + nt*16 + col;
            bfr[nt] = *(const bf16x8*)(Bs + row*64 + ((quad ^ ((row>>2)&3))*16));
        }
        for (int mt = 0; mt < 4; ++mt)
            for (int nt = 0; nt < 4; ++nt)
                acc[mt][nt] = __builtin_amdgcn_mfma_f32_16x16x32_bf16(afr[mt], bfr[nt], acc[mt][nt], 0, 0, 0);
    }
    bf16* Tc = tri + (long)c * NROW;
    for (int mt = 0; mt < 4; ++mt)
        for (int nt = 0; nt < 4; ++nt)
            for (int reg = 0; reg < 4; ++reg) {
                int m = i0 + wm + mt*16 + quad*4 + reg;
                int n = j0 + wn + nt*16 + col;
                Tc[m*512 + n] = (bf16)acc[mt][nt][reg];
            }
}

// ---------------- k3: out = (LN(tri) @ Pp^T) * gate, LN folded into epilogue (fp32 out) ----------------
__global__ __launch_bounds__(256) void k3_out(
        const bf16* __restrict__ tri, const bf16* __restrict__ Pp,
        const float* __restrict__ S1, const float* __restrict__ S2,
        const bf16* __restrict__ gate, float* __restrict__ out) {
    __shared__ char  AS[32768];           // [128 rows][16 chunks of 16B], chunk swizzle ch^=row&15
    __shared__ float MU[128], RS[128];
    const int t    = threadIdx.x;
    const int w    = t >> 6, lane = t & 63;
    const int col  = lane & 15, quad = lane >> 4;
    const long r0  = (long)blockIdx.x * 128;

    // ---- stage tri tile (c-major global -> row-major LDS with chunk swizzle)
    {
        int rg = t & 31;          // rows rg*4..rg*4+3
        int cb = t >> 5;          // 0..7
        for (int it = 0; it < 16; ++it) {
            int cch = it*8 + cb;
            bf16x4 v = *(const bf16x4*)(tri + (long)cch * NROW + r0 + rg*4);
            int ch = cch >> 3, kk = cch & 7;
            for (int u = 0; u < 4; ++u) {
                int row = rg*4 + u;
                *(bf16*)(AS + row*256 + ((ch ^ (row & 15)) * 16) + kk*2) = v[u];
            }
        }
    }
    __syncthreads();

    // ---- LN stats (permutation-invariant sums; phase-offset chunk order)
    {
        int row = t >> 1, half = t & 1;
        float sum = 0.f, ss = 0.f;
        for (int cc = 0; cc < 8; ++cc) {
            int j = (half*8 + cc + row) & 15;
            bf16x8 v = *(const bf16x8*)(AS + row*256 + j*16);
            for (int jj = 0; jj < 8; ++jj) { float f = (float)v[jj]; sum += f; ss += f*f; }
        }
        sum += __shfl_xor(sum, 1, 64);
        ss  += __shfl_xor(ss, 1, 64);
        float mu  = sum * (1.f/128.f);
        float var = ss  * (1.f/128.f) - mu*mu;
        float rs  = rsqrtf(var + 1e-5f);
        if (half == 0) { MU[row] = mu; RS[row] = rs; }
    }
    __syncthreads();

    const int wm = (w >> 1)*64, wn = (w & 1)*64;
    floatx4 acc[4][4];
    for (int mt = 0; mt < 4; ++mt)
        for (int nt = 0; nt < 4; ++nt) { floatx4 z = {0.f,0.f,0.f,0.f}; acc[mt][nt] = z; }

    for (int s = 0; s < 4; ++s) {
        bf16x8 bfr[4];
        for (int nt = 0; nt < 4; ++nt)
            bfr[nt] = *(const bf16x8*)(Pp + (wn + nt*16 + col)*CC + s*32 + quad*8);
        for (int mt = 0; mt < 4; ++mt) {
            int row = wm + mt*16 + col;
            bf16x8 afr = *(const bf16x8*)(AS + row*256 + (((s*4 + quad) ^ (row & 15)) * 16));
            for (int nt = 0; nt < 4; ++nt)
                acc[mt][nt] = __builtin_amdgcn_mfma_f32_16x16x32_bf16(afr, bfr[nt], acc[mt][nt], 0, 0, 0);
        }
    }

    for (int mt = 0; mt < 4; ++mt)
        for (int nt = 0; nt < 4; ++nt) {
            int n = wn + nt*16 + col;
            float s1 = S1[n], s2 = S2[n];
            for (int reg = 0; reg < 4; ++reg) {
                int m = wm + mt*16 + quad*4 + reg;
                float rs = RS[m], mu = MU[m];
                float v  = rs*acc[mt][nt][reg] - rs*mu*s1 + s2;
                float gt = (float)gate[(r0 + m)*CC + n];
                out[(r0 + m)*CC + n] = v * gt;
            }
        }
}

extern "C" void kernel_launch(void* const* d_in, const int* in_sizes, int n_in,
                              void* d_out, int out_size, void* d_ws, size_t ws_size,
                              hipStream_t stream) {
    const float* x       = (const float*)d_in[0];
    const float* nin_w   = (const float*)d_in[1];
    const float* nin_b   = (const float*)d_in[2];
    const float* g_in_w  = (const float*)d_in[3];
    const float* p_in_w  = (const float*)d_in[4];
    const float* g_out_w = (const float*)d_in[5];
    const float* nout_w  = (const float*)d_in[6];
    const float* nout_b  = (const float*)d_in[7];
    const float* p_out_w = (const float*)d_in[8];

    char* ws = (char*)d_ws;
    bf16*  Wall = (bf16*)(ws);                      // 640*128*2 = 163840
    float* T1   = (float*)(ws + 163840);            // 2560
    float* T2   = (float*)(ws + 166400);            // 2560
    bf16*  Pp   = (bf16*)(ws + 168960);             // 32768
    float* S1   = (float*)(ws + 201728);            // 512
    float* S2   = (float*)(ws + 202240);            // 512
    const long BIG = 67108864L;                     // 262144*128*2 bytes
    bf16* a_t  = (bf16*)(ws + 204800);
    bf16* b_t  = (bf16*)(ws + 204800 + BIG);
    bf16* gate = (bf16*)(ws + 204800 + 2*BIG);
    bf16* tri  = (bf16*)(ws + 204800 + 3*BIG);
    float* outp = (float*)d_out;

    setup_kernel<<<3, 256, 0, stream>>>(nin_w, nin_b, g_in_w, p_in_w, g_out_w,
                                        nout_w, nout_b, p_out_w,
                                        Wall, T1, T2, Pp, S1, S2);
    k1_ln_proj<<<4096, 256, 0, stream>>>(x, Wall, T1, T2, a_t, b_t, gate);
    k2_tri<<<dim3(16, 128), 256, 0, stream>>>(a_t, b_t, tri);
    k3_out<<<2048, 256, 0, stream>>>(tri, Pp, S1, S2, gate, outp);
}

// Round 3
// 537.212 us; speedup vs baseline: 1.0756x; 1.0756x over previous
//
#include <hip/hip_runtime.h>

typedef __bf16 bf16;
typedef __bf16 bf16x4 __attribute__((ext_vector_type(4)));
typedef __bf16 bf16x8 __attribute__((ext_vector_type(8)));
typedef float floatx4 __attribute__((ext_vector_type(4)));

#define NN 512
#define CC 128
#define NROW (NN*NN)   // 262144 rows

__device__ __forceinline__ void async16(void* lds, const void* g) {
    __builtin_amdgcn_global_load_lds((const __attribute__((address_space(1))) void*)g,
                                     (__attribute__((address_space(3))) void*)lds, 16, 0, 0);
}
__device__ __forceinline__ void wait_vm0() {
    asm volatile("s_waitcnt vmcnt(0)" ::: "memory");
}
__device__ __forceinline__ float sigmoidf(float x) {
    return __builtin_amdgcn_rcpf(1.f + __expf(-x));
}

// ---------------- setup: W' = W*nw (640x128 bf16), t1=sum(nw*W), t2=sum(nb*W); same for p_out ----------------
__global__ void setup_kernel(const float* __restrict__ nin_w, const float* __restrict__ nin_b,
                             const float* __restrict__ g_in_w, const float* __restrict__ p_in_w,
                             const float* __restrict__ g_out_w,
                             const float* __restrict__ nout_w, const float* __restrict__ nout_b,
                             const float* __restrict__ p_out_w,
                             bf16* __restrict__ Wall, float* __restrict__ T1, float* __restrict__ T2,
                             bf16* __restrict__ Pp, float* __restrict__ S1, float* __restrict__ S2) {
    int r = blockIdx.x * 256 + threadIdx.x;
    if (r < 640) {
        const float* src = (r < 256) ? (g_in_w + r*CC)
                         : (r < 512) ? (p_in_w + (r-256)*CC)
                                     : (g_out_w + (r-512)*CC);
        float t1 = 0.f, t2 = 0.f;
        for (int c = 0; c < CC; ++c) {
            float wv = src[c];
            float wn = nin_w[c];
            float bn = nin_b[c];
            Wall[r*CC + c] = (bf16)(wv * wn);
            t1 += wn * wv;
            t2 += bn * wv;
        }
        T1[r] = t1; T2[r] = t2;
    } else if (r < 768) {
        int d = r - 640;
        const float* src = p_out_w + d*CC;
        float t1 = 0.f, t2 = 0.f;
        for (int c = 0; c < CC; ++c) {
            float wv = src[c];
            float wn = nout_w[c];
            float bn = nout_b[c];
            Pp[d*CC + c] = (bf16)(wv * wn);
            t1 += wn * wv;
            t2 += bn * wv;
        }
        S1[d] = t1; S2[d] = t2;
    }
}

// ---------------- k1: fused LN-in + [g_in|p_in|g_out] projections (fp32 x input) ----------------
// block = 256 thr (4 waves), 64 rows/block. LN folded into GEMM epilogue.
// outputs: a_t[c][r], b_t[c][r] (bf16, c-major for tri GEMM), gate[r][d] (bf16).
__global__ __launch_bounds__(256) void k1_ln_proj(
        const float* __restrict__ x, const bf16* __restrict__ Wall,
        const float* __restrict__ T1, const float* __restrict__ T2,
        bf16* __restrict__ a_t, bf16* __restrict__ b_t, bf16* __restrict__ gate) {
    __shared__ char  XS[32768];          // 4 slabs x [64 rows][32 floats], 16B chunks swizzled p = c ^ (row&7)
    __shared__ float MU[64], RS[64];
    // transpose buffers aliased into XS (dead after A-frag load): per wave 16c x 144B

    const int t    = threadIdx.x;
    const int w    = t >> 6, lane = t & 63;
    const int col  = lane & 15, quad = lane >> 4;
    const long r0  = (long)blockIdx.x * 64;

    // ---- stage raw fp32 x rows (64 x 128 f32 = 32KB) into 4 k-slabs, source-chunk swizzled
    const char* xg = (const char*)(x + r0 * CC);
    for (int q = 0; q < 8; ++q) {
        int L = q*4096 + t*16;
        int s = L >> 13, row = (L >> 7) & 63, p = (L >> 4) & 7;
        int c = p ^ (row & 7);
        async16(XS + L, xg + row*512 + s*128 + c*16);
    }
    wait_vm0();
    __syncthreads();

    // ---- LN stats (4 threads per row; each sums one slab, phase-offset chunks)
    {
        int row = t >> 2, part = t & 3;
        float sum = 0.f, ss = 0.f;
        for (int ch = 0; ch < 8; ++ch) {
            int p = (ch + row + part*2) & 7;
            floatx4 v = *(const floatx4*)(XS + part*8192 + row*128 + p*16);
            for (int j = 0; j < 4; ++j) { float f = v[j]; sum += f; ss += f*f; }
        }
        sum += __shfl_xor(sum, 1, 64); ss += __shfl_xor(ss, 1, 64);
        sum += __shfl_xor(sum, 2, 64); ss += __shfl_xor(ss, 2, 64);
        float mu  = sum * (1.f/128.f);
        float var = ss  * (1.f/128.f) - mu*mu;
        float rs  = rsqrtf(var + 1e-5f);
        if (part == 0) { MU[row] = mu; RS[row] = rs; }
    }
    __syncthreads();

    // ---- A fragments: fp32 LDS -> bf16 registers
    bf16x8 af[4][4];
    for (int mt = 0; mt < 4; ++mt) {
        int row = mt*16 + col;
        for (int s = 0; s < 4; ++s) {
            floatx4 f0 = *(const floatx4*)(XS + s*8192 + row*128 + (((quad*2+0) ^ (row&7))*16));
            floatx4 f1 = *(const floatx4*)(XS + s*8192 + row*128 + (((quad*2+1) ^ (row&7))*16));
            bf16x8 v;
            v[0]=(bf16)f0[0]; v[1]=(bf16)f0[1]; v[2]=(bf16)f0[2]; v[3]=(bf16)f0[3];
            v[4]=(bf16)f1[0]; v[5]=(bf16)f1[1]; v[6]=(bf16)f1[2]; v[7]=(bf16)f1[3];
            af[mt][s] = v;
        }
    }
    float muL[4], rsL[4];
    for (int mt = 0; mt < 4; ++mt) {
        muL[mt] = MU[mt*16 + quad*4 + 0];   // per-reg handled below via direct reads
        rsL[mt] = RS[mt*16 + quad*4 + 0];
    }
    (void)muL; (void)rsL;
    __syncthreads();                        // XS now dead -> reuse as transpose buffers
    char* TBw = XS + w*2304;                // 16 x 144B per wave

    // ---- GEMM: jobs 0..15 = pg (g&p cols job*16..), jobs 16..23 = gate cols
    for (int jj = 0; jj < 6; ++jj) {
        int job = w + jj*4;
        if (job < 16) {
            bf16x8 bg[4], bp[4];
            for (int s = 0; s < 4; ++s) {
                bg[s] = *(const bf16x8*)(Wall + (      job*16 + col)*CC + s*32 + quad*8);
                bp[s] = *(const bf16x8*)(Wall + (256 + job*16 + col)*CC + s*32 + quad*8);
            }
            int dg = job*16 + col, dp = 256 + job*16 + col;
            float t1g = T1[dg], t2g = T2[dg], t1p = T1[dp], t2p = T2[dp];
            bf16* dst = (job < 8) ? a_t : b_t;
            int cbase = (job < 8 ? job : job - 8) * 16;
            for (int mt = 0; mt < 4; ++mt) {
                floatx4 ag = {0.f,0.f,0.f,0.f}, ap = {0.f,0.f,0.f,0.f};
            #pragma unroll
                for (int s = 0; s < 4; ++s) {
                    ag = __builtin_amdgcn_mfma_f32_16x16x32_bf16(af[mt][s], bg[s], ag, 0, 0, 0);
                    ap = __builtin_amdgcn_mfma_f32_16x16x32_bf16(af[mt][s], bp[s], ap, 0, 0, 0);
                }
                bf16x4 pk;
            #pragma unroll
                for (int reg = 0; reg < 4; ++reg) {
                    int m = mt*16 + quad*4 + reg;
                    float rs = RS[m], mu = MU[m];
                    float g = rs*ag[reg] - rs*mu*t1g + t2g;
                    float p = rs*ap[reg] - rs*mu*t1p + t2p;
                    pk[reg] = (bf16)(p * sigmoidf(g));
                }
                // wave-private transpose buffer: [c=col][r = mt*16+quad*4 ..+3]
                *(bf16x4*)(TBw + col*144 + mt*32 + quad*8) = pk;
            }
            // read back transposed: lane -> c = lane>>2, two 8-row chunks
            {
                int c  = lane >> 2;
                int c0 = lane & 3, c1 = (lane & 3) + 4;
                bf16x8 r0v = *(const bf16x8*)(TBw + c*144 + c0*16);
                bf16x8 r1v = *(const bf16x8*)(TBw + c*144 + c1*16);
                bf16* base = dst + (long)(cbase + c) * NROW + r0;
                *(bf16x8*)(base + c0*8) = r0v;
                *(bf16x8*)(base + c1*8) = r1v;
            }
        } else {
            int gc = job - 16;
            bf16x8 bgt[4];
            for (int s = 0; s < 4; ++s)
                bgt[s] = *(const bf16x8*)(Wall + (512 + gc*16 + col)*CC + s*32 + quad*8);
            int dd = 512 + gc*16 + col;
            float t1 = T1[dd], t2 = T2[dd];
            for (int mt = 0; mt < 4; ++mt) {
                floatx4 ac = {0.f,0.f,0.f,0.f};
            #pragma unroll
                for (int s = 0; s < 4; ++s)
                    ac = __builtin_amdgcn_mfma_f32_16x16x32_bf16(af[mt][s], bgt[s], ac, 0, 0, 0);
            #pragma unroll
                for (int reg = 0; reg < 4; ++reg) {
                    int m = mt*16 + quad*4 + reg;
                    float rs = RS[m], mu = MU[m];
                    float g = rs*ac[reg] - rs*mu*t1 + t2;
                    gate[(r0 + m)*CC + gc*16 + col] = (bf16)sigmoidf(g);
                }
            }
        }
    }
}

// ---------------- k2: tri[c] = A_c * B_c^T  (128 independent 512^3 bf16 GEMMs), 256x128 tiles ----------------
__global__ __launch_bounds__(256, 2) void k2_tri(
        const bf16* __restrict__ a_t, const bf16* __restrict__ b_t, bf16* __restrict__ tri) {
    __shared__ char As[16384], Bs[8192];   // [rows][32 bf16], 16B chunks swizzled p = c ^ ((row>>2)&3)
    const int t    = threadIdx.x;
    const int w    = t >> 6, lane = t & 63;
    const int col  = lane & 15, quad = lane >> 4;
    const int c    = blockIdx.y;
    const int i0   = (blockIdx.x >> 2) * 256, j0 = (blockIdx.x & 3) * 128;
    const char* Ac = (const char*)(a_t + (long)c * NROW);
    const char* Bc = (const char*)(b_t + (long)c * NROW);
    const int wm = w * 64;                 // wave tile: 64 m x 128 n

    floatx4 acc[4][8];
    for (int mt = 0; mt < 4; ++mt)
        for (int nt = 0; nt < 8; ++nt) { floatx4 z = {0.f,0.f,0.f,0.f}; acc[mt][nt] = z; }

    for (int k0 = 0; k0 < 512; k0 += 32) {
        __syncthreads();
        for (int q = 0; q < 4; ++q) {
            int L = q*4096 + t*16;
            int row = L >> 6, p = (L >> 4) & 3;
            int cl = p ^ ((row >> 2) & 3);
            async16(As + L, Ac + (i0 + row)*1024 + k0*2 + cl*16);
        }
        for (int q = 0; q < 2; ++q) {
            int L = q*4096 + t*16;
            int row = L >> 6, p = (L >> 4) & 3;
            int cl = p ^ ((row >> 2) & 3);
            async16(Bs + L, Bc + (j0 + row)*1024 + k0*2 + cl*16);
        }
        wait_vm0();
        __syncthreads();
        bf16x8 afr[4], bfr[8];
        for (int mt = 0; mt < 4; ++mt) {
            int row = wm + mt*16 + col;
            afr[mt] = *(const bf16x8*)(As + row*64 + ((quad ^ ((row>>2)&3))*16));
        }
        for (int nt = 0; nt < 8; ++nt) {
            int row = nt*16 + col;
            bfr[nt] = *(const bf16x8*)(Bs + row*64 + ((quad ^ ((row>>2)&3))*16));
        }
        for (int mt = 0; mt < 4; ++mt)
            for (int nt = 0; nt < 8; ++nt)
                acc[mt][nt] = __builtin_amdgcn_mfma_f32_16x16x32_bf16(afr[mt], bfr[nt], acc[mt][nt], 0, 0, 0);
    }
    bf16* Tc = tri + (long)c * NROW;
    for (int mt = 0; mt < 4; ++mt)
        for (int nt = 0; nt < 8; ++nt)
            for (int reg = 0; reg < 4; ++reg) {
                int m = i0 + wm + mt*16 + quad*4 + reg;
                int n = j0 + nt*16 + col;
                Tc[m*512 + n] = (bf16)acc[mt][nt][reg];
            }
}

// ---------------- k3: out = (LN(tri) @ Pp^T) * gate, LN folded into epilogue (fp32 out) ----------------
__global__ __launch_bounds__(256) void k3_out(
        const bf16* __restrict__ tri, const bf16* __restrict__ Pp,
        const float* __restrict__ S1, const float* __restrict__ S2,
        const bf16* __restrict__ gate, float* __restrict__ out) {
    __shared__ char  AS[128*272];         // [128 r][128 c bf16], row stride 272B (16-aligned, bank-spread)
    __shared__ float MU[128], RS[128];
    const int t    = threadIdx.x;
    const int w    = t >> 6, lane = t & 63;
    const int col  = lane & 15, quad = lane >> 4;
    const long r0  = (long)blockIdx.x * 128;

    // ---- stage tri tile: gather 4 c-planes per lane (coalesced 2B loads), ds_write_b64
    for (int it = 0; it < 16; ++it) {
        int rl = (it & 1)*64 + (t & 63);
        int cq = (it >> 1)*4 + (t >> 6);
        const bf16* src = tri + (long)(cq*4) * NROW + r0 + rl;
        bf16x4 v;
        v[0] = src[0];
        v[1] = src[NROW];
        v[2] = src[2*NROW];
        v[3] = src[3*NROW];
        *(bf16x4*)(AS + rl*272 + cq*8) = v;
    }
    __syncthreads();

    // ---- LN stats
    {
        int row = t >> 1, half = t & 1;
        float sum = 0.f, ss = 0.f;
        for (int j = 0; j < 8; ++j) {
            bf16x8 v = *(const bf16x8*)(AS + row*272 + (half*8 + j)*16);
            for (int jj = 0; jj < 8; ++jj) { float f = (float)v[jj]; sum += f; ss += f*f; }
        }
        sum += __shfl_xor(sum, 1, 64);
        ss  += __shfl_xor(ss, 1, 64);
        float mu  = sum * (1.f/128.f);
        float var = ss  * (1.f/128.f) - mu*mu;
        float rs  = rsqrtf(var + 1e-5f);
        if (half == 0) { MU[row] = mu; RS[row] = rs; }
    }
    __syncthreads();

    const int wm = (w >> 1)*64, wn = (w & 1)*64;
    floatx4 acc[4][4];
    for (int mt = 0; mt < 4; ++mt)
        for (int nt = 0; nt < 4; ++nt) { floatx4 z = {0.f,0.f,0.f,0.f}; acc[mt][nt] = z; }

    for (int s = 0; s < 4; ++s) {
        bf16x8 bfr[4];
        for (int nt = 0; nt < 4; ++nt)
            bfr[nt] = *(const bf16x8*)(Pp + (wn + nt*16 + col)*CC + s*32 + quad*8);
        for (int mt = 0; mt < 4; ++mt) {
            int row = wm + mt*16 + col;
            bf16x8 afr = *(const bf16x8*)(AS + row*272 + s*64 + quad*16);
            for (int nt = 0; nt < 4; ++nt)
                acc[mt][nt] = __builtin_amdgcn_mfma_f32_16x16x32_bf16(afr, bfr[nt], acc[mt][nt], 0, 0, 0);
        }
    }

    for (int mt = 0; mt < 4; ++mt)
        for (int nt = 0; nt < 4; ++nt) {
            int n = wn + nt*16 + col;
            float s1 = S1[n], s2 = S2[n];
            for (int reg = 0; reg < 4; ++reg) {
                int m = wm + mt*16 + quad*4 + reg;
                float rs = RS[m], mu = MU[m];
                float v  = rs*acc[mt][nt][reg] - rs*mu*s1 + s2;
                float gt = (float)gate[(r0 + m)*CC + n];
                out[(r0 + m)*CC + n] = v * gt;
            }
        }
}

extern "C" void kernel_launch(void* const* d_in, const int* in_sizes, int n_in,
                              void* d_out, int out_size, void* d_ws, size_t ws_size,
                              hipStream_t stream) {
    const float* x       = (const float*)d_in[0];
    const float* nin_w   = (const float*)d_in[1];
    const float* nin_b   = (const float*)d_in[2];
    const float* g_in_w  = (const float*)d_in[3];
    const float* p_in_w  = (const float*)d_in[4];
    const float* g_out_w = (const float*)d_in[5];
    const float* nout_w  = (const float*)d_in[6];
    const float* nout_b  = (const float*)d_in[7];
    const float* p_out_w = (const float*)d_in[8];

    char* ws = (char*)d_ws;
    bf16*  Wall = (bf16*)(ws);                      // 640*128*2 = 163840
    float* T1   = (float*)(ws + 163840);            // 2560
    float* T2   = (float*)(ws + 166400);            // 2560
    bf16*  Pp   = (bf16*)(ws + 168960);             // 32768
    float* S1   = (float*)(ws + 201728);            // 512
    float* S2   = (float*)(ws + 202240);            // 512
    const long BIG = 67108864L;                     // 262144*128*2 bytes
    bf16* a_t  = (bf16*)(ws + 204800);
    bf16* b_t  = (bf16*)(ws + 204800 + BIG);
    bf16* gate = (bf16*)(ws + 204800 + 2*BIG);
    bf16* tri  = (bf16*)(ws + 204800 + 3*BIG);
    float* outp = (float*)d_out;

    setup_kernel<<<3, 256, 0, stream>>>(nin_w, nin_b, g_in_w, p_in_w, g_out_w,
                                        nout_w, nout_b, p_out_w,
                                        Wall, T1, T2, Pp, S1, S2);
    k1_ln_proj<<<4096, 256, 0, stream>>>(x, Wall, T1, T2, a_t, b_t, gate);
    k2_tri<<<dim3(8, 128), 256, 0, stream>>>(a_t, b_t, tri);
    k3_out<<<2048, 256, 0, stream>>>(tri, Pp, S1, S2, gate, outp);
}